// Round 1
// baseline (434.400 us; speedup 1.0000x reference)
//
#include <hip/hip_runtime.h>
#include <hip/hip_cooperative_groups.h>
#include <math.h>

// CRITICAL: ban FMA contraction file-wide. 1-ulp iou shifts flip near-tie
// argmaxes vs numpy's correctly-rounded ref (rounds 2-4, absmax 69).
#pragma clang fp contract(off)

namespace cg = cooperative_groups;

// Shapes: B=64, N=100, A=8732.
// Out layout (f32 flat): [0,BA) labels | [BA,5BA) boxes | [5BA,6BA) mask
// iou pass writes ONLY the slot array (mask region): bi | 0x8000 pos bit.
// colmax u64[B*N] at out+BA (boxes region): initialized by prior phase,
// atomicMax'd by iou phase, consumed by scatter phase, overwritten by encode.
// d_ws: prior f32[B*N] = 25,600 B (proven-safe size).
//
// THIS ROUND: fuse all 4 dispatches into ONE cooperative kernel with
// grid.sync() between phases. Phase bodies are byte-identical to the
// HW-proven 4-kernel pipeline (kept below as the fallback path).
// Scatter stays its own phase (behind a sync): colmax bytes alias the
// boxes region that encode overwrites — fusing scatter into encode would
// race cross-block colmax reads vs boxes writes.

#define AA 8732
#define NN 100
#define BB 64
#define NTILE 35              // ceil(AA/256)
#define NT (BB * NTILE)       // 2240 row/encode tiles
#define EPS_F 1e-6f
#define OVR_FLAG 0x10000
#define POS_BIT  0x8000
// qa = inter*v_rcp(uni): rel err <= ~1.8e-7. DEFL=1-5e-7 deflation makes all
// filters rigorous one-sided bounds (HW-validated rounds 8/10/11).
#define DEFL 0.9999995f

__constant__ int FM_SIZE[6] = {38, 19, 10, 5, 3, 1};
__constant__ int FM_NF[6]   = {4, 6, 6, 6, 4, 4};
__constant__ int FM_OFF[6]  = {0, 5776, 7942, 8542, 8692, 8728};

__device__ __forceinline__ void geom(const float4 axy, const float4 g,
                                     float area_a, float ag,
                                     float& inter, float& uni) {
    float ltx = fmaxf(axy.x, g.x);
    float lty = fmaxf(axy.y, g.y);
    float rbx = fminf(axy.z, g.z);
    float rby = fminf(axy.w, g.w);
    float w = fmaxf(rbx - ltx, 0.0f);
    float h = fmaxf(rby - lty, 0.0f);
    inter = w * h;
    uni = area_a + ag - inter;       // uni >= max area > 0 always
}

// ---------------------------------------------------------------------------
// Prior: per (b,n), rcp-approx max IoU over the <=30 center-cell anchors,
// deflated => SAFE lower bound of the column max (< true bits strictly).
// Also initializes colmax with (prior_bits<<32 | 0): low=0 loses all ties to
// genuine submissions (low>=1), so the real winner always lands.
// ---------------------------------------------------------------------------
__device__ __forceinline__ void prior_one(
        const int b, const int n,
        const float4* __restrict__ gt_boxes,
        const float4* __restrict__ anchors_xyxy,
        float* __restrict__ prior,
        unsigned long long* __restrict__ colmax)
{
    float4 g = gt_boxes[b * NN + n];
    float ag = (g.z - g.x) * (g.w - g.y);
    float cx = (g.x + g.z) * 0.5f;
    float cy = (g.y + g.w) * 0.5f;
    float best = 0.0f;
    for (int f = 0; f < 6; f++) {
        int s = FM_SIZE[f];
        int j = (int)(cx * (float)s); j = j < s - 1 ? j : s - 1;
        int i = (int)(cy * (float)s); i = i < s - 1 ? i : s - 1;
        int base = FM_OFF[f] + (i * s + j) * FM_NF[f];
        for (int k = 0; k < FM_NF[f]; k++) {
            float4 an = anchors_xyxy[base + k];
            float area_a = (an.z - an.x) * (an.w - an.y);
            float inter, uni;
            geom(an, g, area_a, ag, inter, uni);
            best = fmaxf(best, inter * __builtin_amdgcn_rcpf(uni));
        }
    }
    float defl = best * DEFL;        // <= colM*(1-3.2e-7): safe lower bound
    prior[b * NN + n] = defl;
    colmax[b * NN + n] = ((unsigned long long)__float_as_uint(defl)) << 32;
}

// ---------------------------------------------------------------------------
// Main-pass chunk [N0,N1): 1 anchor/thread. Row: record mask vs pre-deflated
// running threshold rt (loop-carried chain is a single fmax; qa*DEFL is off
// the critical path); exact div deferred. Col: 1-cmp __any trigger vs LDS
// scurf (rare after prior priming); on trigger, exact div + packed u64
// butterfly ((bits<<32)|(AA-a): max iou then lowest a), lane 0 submits
// atomicMax + scurf warm-up. Clamped clone lanes carry anchor AA-1's genuine
// packed value — idempotent under max.
// ---------------------------------------------------------------------------
template <int N0, int N1>
__device__ __forceinline__ void passChunk(
        const float4 axy, const float area_a, const unsigned lowkey,
        const int b, const int tid,
        const float4* __restrict__ sg,
        float2* sac,                                // x=area, y=scurf
        unsigned long long* __restrict__ colmax,
        float& rt, unsigned& rm)
{
    #pragma unroll 4
    for (int n = N0; n < N1; n++) {
        float4 g = sg[n];
        float2 aw = sac[n];        // one ds_read_b64 (stale .y = superset, safe)
        float inter, uni;
        geom(axy, g, area_a, aw.x, inter, uni);
        float qa = inter * __builtin_amdgcn_rcpf(uni);
        bool r = (qa > 0.0f) && (qa >= rt);          // row near-record
        rt = fmaxf(rt, qa * DEFL);
        rm |= (r ? 1u : 0u) << (n - N0);
        if (__any((int)(qa >= aw.y))) {              // column trigger (rare)
            float iou = inter / uni;                 // exact IEEE == numpy
            bool cc = (qa >= aw.y);
            unsigned long long p = cc
                ? ((((unsigned long long)__float_as_uint(iou)) << 32) |
                   (unsigned long long)lowkey) : 0ull;
            #pragma unroll
            for (int off = 32; off > 0; off >>= 1) {
                unsigned long long o = __shfl_xor(p, off);
                p = o > p ? o : p;
            }
            if ((tid & 63) == 0 && p != 0ull) {
                atomicMax(colmax + b * NN + n, p);
                atomicMax((unsigned*)&sac[n].y,
                    __float_as_uint(__uint_as_float((unsigned)(p >> 32)) * DEFL));
            }
        }
    }
}

// One row-pass tile (b, 256-anchor chunk c). Stages LDS itself; caller must
// __syncthreads() between consecutive tiles on the same block.
__device__ __forceinline__ void iou_tile(
        const int b, const int c, const int tid,
        const float4* __restrict__ gt_boxes,
        const float4* __restrict__ anchors_xyxy,
        const float* __restrict__ prior,
        unsigned long long* __restrict__ colmax,
        int* __restrict__ out_slot,
        float4* __restrict__ sg, float2* sac)
{
    if (tid < NN) {
        float4 g = gt_boxes[b * NN + tid];
        sg[tid] = g;
        sac[tid] = make_float2((g.z - g.x) * (g.w - g.y),
                               prior[b * NN + tid]);
    }
    __syncthreads();

    const int a = c * 256 + tid;
    const bool valid = (a < AA);
    const int ac = valid ? a : (AA - 1);
    const float4 axy = anchors_xyxy[ac];
    const float area_a = (axy.z - axy.x) * (axy.w - axy.y);
    const unsigned lowkey = (unsigned)(AA - ac);    // bigger = lower anchor

    // ---------------- Phase A ----------------
    float rt = 0.0f;               // running (deflated) row-record threshold
    unsigned rm0 = 0, rm1 = 0, rm2 = 0, rm3 = 0;
    passChunk<0, 32>(axy, area_a, lowkey, b, tid, sg, sac, colmax, rt, rm0);
    passChunk<32, 64>(axy, area_a, lowkey, b, tid, sg, sac, colmax, rt, rm1);
    passChunk<64, 96>(axy, area_a, lowkey, b, tid, sg, sac, colmax, rt, rm2);
    passChunk<96, NN>(axy, area_a, lowkey, b, tid, sg, sac, colmax, rt, rm3);

    // ---------------- Phase B: row replay (ascending n = numpy order) -----
    float bv = 0.0f;   // all-zero row: bv=0, bi=0 == numpy argmax
    int bi = 0;
    unsigned rms[4] = {rm0, rm1, rm2, rm3};
    #pragma unroll
    for (int h = 0; h < 4; h++) {
        unsigned m = rms[h];
        const int nb = h * 32;
        while (m) {
            int n = __builtin_ctz(m) + nb;
            m &= m - 1;
            float inter, uni;
            geom(axy, sg[n], area_a, sac[n].x, inter, uni);
            float qa = inter * __builtin_amdgcn_rcpf(uni);
            if (qa > 0.0f && qa >= rt) {             // final-threshold re-test
                float iou = inter / uni;             // exact IEEE == numpy
                if (iou > bv) { bv = iou; bi = n; }  // strict >: first max
            }
        }
    }

    if (valid) {
        out_slot[(size_t)b * AA + a] = bi | (bv > 0.5f ? POS_BIT : 0);
    }
}

// One encode tile (b, 256-anchor chunk c). Caller syncs between tiles.
__device__ __forceinline__ void encode_tile(
        const int b, const int c, const int tid,
        const int* __restrict__ gt_labels,
        const float4* __restrict__ gt_boxes,        // xyxy
        const float4* __restrict__ anchors_cxcywh,
        float* __restrict__ out,
        float4* __restrict__ sg, int* __restrict__ slab)
{
    if (tid < NN) {
        sg[tid]   = gt_boxes[b * NN + tid];
        slab[tid] = gt_labels[b * NN + tid];
    }
    __syncthreads();

    const int a = c * 256 + tid;
    if (a < AA) {
        const size_t BA = (size_t)BB * AA;
        const size_t base = (size_t)b * AA + a;

        int s = ((const int*)(out + 5 * BA))[base];

        int idx; bool pos;
        if (s >= OVR_FLAG) { idx = s - OVR_FLAG;  pos = true; }
        else               { idx = s & 0x7FFF;    pos = (s & POS_BIT) != 0; }

        const float4 g = sg[idx];
        const float gcx = (g.x + g.z) * 0.5f;
        const float gcy = (g.y + g.w) * 0.5f;
        const float gw  = g.z - g.x;
        const float gh  = g.w - g.y;

        const float4 anc = anchors_cxcywh[a];
        const float ecx = (gcx - anc.x) / anc.z;
        const float ecy = (gcy - anc.y) / anc.w;
        const float ew  = logf((gw + EPS_F) / (anc.z + EPS_F));
        const float eh  = logf((gh + EPS_F) / (anc.w + EPS_F));

        out[base] = pos ? (float)slab[idx] : 0.0f;                   // labels
        ((float4*)(out + BA))[base] = make_float4(ecx, ecy, ew, eh); // boxes
        out[5 * BA + base] = pos ? 1.0f : 0.0f;                      // mask
    }
}

// ---------------------------------------------------------------------------
// Cooperative mega-kernel: prior -> sync -> iou -> sync -> scatter -> sync
// -> encode. 8 blocks/CU co-residency enforced via __launch_bounds__(256,8)
// (VGPR capped at 64; phases are sequential so pressure = max per phase).
// ---------------------------------------------------------------------------
__global__ __launch_bounds__(256, 8) void mega_kernel(
        const int* __restrict__ gt_labels,
        const float4* __restrict__ gt_boxes,
        const float4* __restrict__ anchors_cxcywh,
        const float4* __restrict__ anchors_xyxy,
        float* __restrict__ out,
        float* __restrict__ prior)
{
    cg::grid_group grid = cg::this_grid();
    const int tid = threadIdx.x;
    const int bid = blockIdx.x;
    const int nb  = gridDim.x;
    const size_t BA = (size_t)BB * AA;
    unsigned long long* colmax = (unsigned long long*)(out + BA);
    int* out_slot = (int*)(out + 5 * BA);

    __shared__ float4 sg[NN];
    __shared__ float2 sac[NN];
    __shared__ int    slab[NN];

    // ---- phase 0: prior + colmax init (6400 flat tasks, blocks 0..24) ----
    {
        const int g = bid * 256 + tid;
        if (g < BB * NN) {
            const int b = g / NN;
            prior_one(b, g - b * NN, gt_boxes, anchors_xyxy, prior, colmax);
        }
    }
    grid.sync();

    // ---- phase 1: row pass, grid-stride over 2240 tiles ----
    for (int t = bid; t < NT; t += nb) {
        const int b = t / NTILE;
        const int c = t - b * NTILE;
        iou_tile(b, c, tid, gt_boxes, anchors_xyxy, prior, colmax, out_slot,
                 sg, sac);
        __syncthreads();   // LDS drained before next tile's restage
    }
    grid.sync();

    // ---- phase 2: scatter gt->anchor override (np last-n-wins == atomicMax
    //      over OVR_FLAG+n; low==0 prior sentinel rejected by guard) ----
    {
        const int g = bid * 256 + tid;
        if (g < BB * NN) {
            const int b = g / NN;
            const int n = g - b * NN;
            unsigned long long v = colmax[g];
            unsigned low = (unsigned)(v & 0xFFFFFFFFull);
            if (low >= 1u && low <= (unsigned)AA) {
                int idx = AA - (int)low;
                atomicMax(&out_slot[(size_t)b * AA + idx], OVR_FLAG + n);
            }
        }
    }
    grid.sync();

    // ---- phase 3: encode (overwrites boxes region incl. colmax bytes) ----
    for (int t = bid; t < NT; t += nb) {
        const int b = t / NTILE;
        const int c = t - b * NTILE;
        encode_tile(b, c, tid, gt_labels, gt_boxes, anchors_cxcywh, out,
                    sg, slab);
        __syncthreads();
    }
}

// ---------------------------------------------------------------------------
// Fallback path: the HW-proven 4-kernel pipeline (used only if cooperative
// launch is unavailable/refused — correctness insurance, identical math).
// ---------------------------------------------------------------------------
__global__ void prior_kernel(const float4* __restrict__ gt_boxes,
                             const float4* __restrict__ anchors_xyxy,
                             float* __restrict__ prior,
                             unsigned long long* __restrict__ colmax) {
    const int b = blockIdx.x;
    const int n = threadIdx.x;
    if (n >= NN) return;
    prior_one(b, n, gt_boxes, anchors_xyxy, prior, colmax);
}

__global__ __launch_bounds__(256) void iou_pass_kernel(
        const float4* __restrict__ gt_boxes,
        const float4* __restrict__ anchors_xyxy,
        const float* __restrict__ prior,
        unsigned long long* __restrict__ colmax,
        int* __restrict__ out_slot)
{
    __shared__ float4 sg[NN];
    __shared__ float2 sac[NN];
    iou_tile(blockIdx.y, blockIdx.x, threadIdx.x,
             gt_boxes, anchors_xyxy, prior, colmax, out_slot, sg, sac);
}

__global__ void scatter_kernel(const unsigned long long* __restrict__ colmax,
                               int* __restrict__ out_slot) {
    const int b = blockIdx.x;
    const int n = threadIdx.x;
    if (n < NN) {
        unsigned long long v = colmax[b * NN + n];
        unsigned low = (unsigned)(v & 0xFFFFFFFFull);
        if (low >= 1u && low <= (unsigned)AA) {
            int idx = AA - (int)low;
            atomicMax(&out_slot[(size_t)b * AA + idx], OVR_FLAG + n);
        }
    }
}

__global__ __launch_bounds__(256) void encode_kernel(
        const int* __restrict__ gt_labels,
        const float4* __restrict__ gt_boxes,
        const float4* __restrict__ anchors_cxcywh,
        float* __restrict__ out)
{
    __shared__ float4 sg[NN];
    __shared__ int    slab[NN];
    encode_tile(blockIdx.y, blockIdx.x, threadIdx.x,
                gt_labels, gt_boxes, anchors_cxcywh, out, sg, slab);
}

extern "C" void kernel_launch(void* const* d_in, const int* in_sizes, int n_in,
                              void* d_out, int out_size, void* d_ws, size_t ws_size,
                              hipStream_t stream) {
    const int*    gt_labels    = (const int*)d_in[0];
    const float4* gt_boxes     = (const float4*)d_in[1];
    const float4* anchors_cxcy = (const float4*)d_in[2];
    const float4* anchors_xyxy = (const float4*)d_in[3];
    float* out = (float*)d_out;

    const size_t BA = (size_t)BB * AA;
    unsigned long long* colmax = (unsigned long long*)(out + BA); // 8B-aligned
    int* slot = (int*)(out + 5 * BA);
    float* prior = (float*)d_ws;        // B*N f32 = 25,600 B (proven size)

    // One-time (host-side, capture-safe) co-residency check for cooperative
    // launch: grid must be <= maxBlocksPerCU * numCUs. Cached statically.
    static int coop_blocks = -1;
    if (coop_blocks < 0) {
        int dev = 0, cus = 0, maxB = 0;
        if (hipGetDevice(&dev) == hipSuccess &&
            hipDeviceGetAttribute(&cus, hipDeviceAttributeMultiprocessorCount,
                                  dev) == hipSuccess &&
            hipOccupancyMaxActiveBlocksPerMultiprocessor(
                &maxB, (const void*)mega_kernel, 256, 0) == hipSuccess &&
            cus > 0 && maxB > 0) {
            long long cap = (long long)maxB * (long long)cus;
            coop_blocks = (int)(cap > 2048 ? 2048 : cap);
            if (coop_blocks < 64) coop_blocks = 0;   // degenerate: fallback
        } else {
            coop_blocks = 0;
        }
    }

    if (coop_blocks > 0) {
        void* args[6] = { (void*)&gt_labels, (void*)&gt_boxes,
                          (void*)&anchors_cxcy, (void*)&anchors_xyxy,
                          (void*)&out, (void*)&prior };
        hipError_t e = hipLaunchCooperativeKernel(
            (const void*)mega_kernel, dim3((unsigned)coop_blocks), dim3(256),
            args, 0, stream);
        if (e == hipSuccess) return;
        coop_blocks = 0;   // permanent fallback on any refusal
    }

    // ---- fallback: proven 4-dispatch pipeline ----
    prior_kernel<<<BB, 128, 0, stream>>>(gt_boxes, anchors_xyxy, prior, colmax);
    dim3 grid(NTILE, BB);    // (35, 64) — 1 anchor/thread
    iou_pass_kernel<<<grid, 256, 0, stream>>>(gt_boxes, anchors_xyxy, prior,
                                              colmax, slot);
    scatter_kernel<<<BB, 128, 0, stream>>>(colmax, slot);
    encode_kernel<<<grid, 256, 0, stream>>>(gt_labels, gt_boxes, anchors_cxcy,
                                            out);
}

// Round 2
// 128.557 us; speedup vs baseline: 3.3790x; 3.3790x over previous
//
#include <hip/hip_runtime.h>
#include <math.h>

// CRITICAL: ban FMA contraction file-wide. 1-ulp iou shifts flip near-tie
// argmaxes vs numpy's correctly-rounded ref (rounds 2-4, absmax 69).
#pragma clang fp contract(off)

// Shapes: B=64, N=100, A=8732.
// Out layout (f32 flat): [0,BA) labels | [BA,5BA) boxes | [5BA,6BA) mask
// iou pass writes ONLY the slot array (mask region): bi | 0x8000 pos bit.
//
// ROUND 2: cooperative fusion REVERTED (grid.sync cost ~100+ us on gfx950:
// round-1 mega_kernel 522 us @ VALUBusy 10%). Back to stream-ordered
// dispatches; instead we (a) delete the prior[] array (scurf == colmax>>32),
// (b) fuse scatter into encode via an LDS override table, which requires
// colmax OUTSIDE out (encode overwrites the boxes region) -> colmax lives in
// d_ws when ws_size >= 51,200 B; otherwise the HW-proven 4-dispatch path
// (colmax in out's boxes region) runs unchanged.
//
// colmax u64[B*N]: initialized by prior_kernel (prior_bits<<32 | 0: low=0
// loses all ties to genuine submissions, low>=1), atomicMax'd by iou_pass,
// consumed by encode (fused) or scatter (fallback).

#define AA 8732
#define NN 100
#define BB 64
#define NTILE 35              // ceil(AA/256)
#define EPS_F 1e-6f
#define OVR_FLAG 0x10000
#define POS_BIT  0x8000
// qa = inter*v_rcp(uni): rel err <= ~1.8e-7. DEFL=1-5e-7 deflation makes all
// filters rigorous one-sided bounds (HW-validated rounds 8/10/11 + analysis:
// staged scurf = colmax_hi*DEFL covers raw-iou-bits colmax entries since
// 1-5e-7 < 1-1.8e-7; prior-only entries get DEFL^2 = looser, still safe).
#define DEFL 0.9999995f

__constant__ int FM_SIZE[6] = {38, 19, 10, 5, 3, 1};
__constant__ int FM_NF[6]   = {4, 6, 6, 6, 4, 4};
__constant__ int FM_OFF[6]  = {0, 5776, 7942, 8542, 8692, 8728};

__device__ __forceinline__ void geom(const float4 axy, const float4 g,
                                     float area_a, float ag,
                                     float& inter, float& uni) {
    float ltx = fmaxf(axy.x, g.x);
    float lty = fmaxf(axy.y, g.y);
    float rbx = fminf(axy.z, g.z);
    float rby = fminf(axy.w, g.w);
    float w = fmaxf(rbx - ltx, 0.0f);
    float h = fmaxf(rby - lty, 0.0f);
    inter = w * h;
    uni = area_a + ag - inter;       // uni >= max area > 0 always
}

// ---------------------------------------------------------------------------
// Prior: per (b,n), rcp-approx max IoU over the <=30 center-cell anchors,
// deflated => SAFE lower bound of the column max (< true bits strictly).
// Initializes colmax with (prior_bits<<32 | 0): low=0 loses all ties to
// genuine submissions (low>=1), so the real winner always lands.
// ---------------------------------------------------------------------------
__global__ void prior_kernel(const float4* __restrict__ gt_boxes,
                             const float4* __restrict__ anchors_xyxy,
                             unsigned long long* __restrict__ colmax) {
    const int b = blockIdx.x;
    const int n = threadIdx.x;
    if (n >= NN) return;
    float4 g = gt_boxes[b * NN + n];
    float ag = (g.z - g.x) * (g.w - g.y);
    float cx = (g.x + g.z) * 0.5f;
    float cy = (g.y + g.w) * 0.5f;
    float best = 0.0f;
    for (int f = 0; f < 6; f++) {
        int s = FM_SIZE[f];
        int j = (int)(cx * (float)s); j = j < s - 1 ? j : s - 1;
        int i = (int)(cy * (float)s); i = i < s - 1 ? i : s - 1;
        int base = FM_OFF[f] + (i * s + j) * FM_NF[f];
        for (int k = 0; k < FM_NF[f]; k++) {
            float4 an = anchors_xyxy[base + k];
            float area_a = (an.z - an.x) * (an.w - an.y);
            float inter, uni;
            geom(an, g, area_a, ag, inter, uni);
            best = fmaxf(best, inter * __builtin_amdgcn_rcpf(uni));
        }
    }
    float defl = best * DEFL;        // <= colM*(1-3.2e-7): safe lower bound
    colmax[b * NN + n] = ((unsigned long long)__float_as_uint(defl)) << 32;
}

// ---------------------------------------------------------------------------
// Main-pass chunk [N0,N1): 1 anchor/thread (2240 blocks: occupancy regime
// proven in r5/r7). Row: record mask vs pre-deflated running threshold rt
// (loop-carried chain is a single fmax; qa*DEFL is off the critical path);
// exact div deferred. Col: 1-cmp __any trigger vs LDS scurf (rare after
// prior priming); on trigger, exact div + packed u64 butterfly
// ((bits<<32)|(AA-a): max iou then lowest a), lane 0 submits atomicMax +
// scurf warm-up. Clamped clone lanes carry anchor AA-1's genuine packed
// value — idempotent under max.
// ---------------------------------------------------------------------------
template <int N0, int N1>
__device__ __forceinline__ void passChunk(
        const float4 axy, const float area_a, const unsigned lowkey,
        const int b, const int tid,
        const float4* __restrict__ sg,
        float2* sac,                                // x=area, y=scurf
        unsigned long long* __restrict__ colmax,
        float& rt, unsigned& rm)
{
    #pragma unroll 4
    for (int n = N0; n < N1; n++) {
        float4 g = sg[n];
        float2 aw = sac[n];        // one ds_read_b64 (stale .y = superset, safe)
        float inter, uni;
        geom(axy, g, area_a, aw.x, inter, uni);
        float qa = inter * __builtin_amdgcn_rcpf(uni);
        bool r = (qa > 0.0f) && (qa >= rt);          // row near-record
        rt = fmaxf(rt, qa * DEFL);
        rm |= (r ? 1u : 0u) << (n - N0);
        if (__any((int)(qa >= aw.y))) {              // column trigger (rare)
            float iou = inter / uni;                 // exact IEEE == numpy
            bool cc = (qa >= aw.y);
            unsigned long long p = cc
                ? ((((unsigned long long)__float_as_uint(iou)) << 32) |
                   (unsigned long long)lowkey) : 0ull;
            #pragma unroll
            for (int off = 32; off > 0; off >>= 1) {
                unsigned long long o = __shfl_xor(p, off);
                p = o > p ? o : p;
            }
            if ((tid & 63) == 0 && p != 0ull) {
                atomicMax(colmax + b * NN + n, p);
                atomicMax((unsigned*)&sac[n].y,
                    __float_as_uint(__uint_as_float((unsigned)(p >> 32)) * DEFL));
            }
        }
    }
}

__global__ __launch_bounds__(256) void iou_pass_kernel(
        const float4* __restrict__ gt_boxes,        // B*N xyxy
        const float4* __restrict__ anchors_xyxy,    // A
        unsigned long long* __restrict__ colmax,    // B*N packed, prior-init
        int* __restrict__ out_slot)                 // -> out[5BA..6BA)
{
    const int b = blockIdx.y;
    const int tid = threadIdx.x;
    const int a = blockIdx.x * 256 + tid;
    const bool valid = (a < AA);
    const int ac = valid ? a : (AA - 1);

    __shared__ float4 sg[NN];
    __shared__ float2 sac[NN];     // x=area_g, y=scurf (deflated lower bound)

    if (tid < NN) {
        float4 g = gt_boxes[b * NN + tid];
        sg[tid] = g;
        // scurf seed == prior value (or a later colmax submission's raw iou
        // bits) re-deflated: rigorous lower bound either way.
        unsigned hi = (unsigned)(colmax[b * NN + tid] >> 32);
        sac[tid] = make_float2((g.z - g.x) * (g.w - g.y),
                               __uint_as_float(hi) * DEFL);
    }
    __syncthreads();

    const float4 axy = anchors_xyxy[ac];
    const float area_a = (axy.z - axy.x) * (axy.w - axy.y);
    const unsigned lowkey = (unsigned)(AA - ac);    // bigger = lower anchor

    // ---------------- Phase A ----------------
    float rt = 0.0f;               // running (deflated) row-record threshold
    unsigned rm0 = 0, rm1 = 0, rm2 = 0, rm3 = 0;
    passChunk<0, 32>(axy, area_a, lowkey, b, tid, sg, sac, colmax, rt, rm0);
    passChunk<32, 64>(axy, area_a, lowkey, b, tid, sg, sac, colmax, rt, rm1);
    passChunk<64, 96>(axy, area_a, lowkey, b, tid, sg, sac, colmax, rt, rm2);
    passChunk<96, NN>(axy, area_a, lowkey, b, tid, sg, sac, colmax, rt, rm3);

    // ---------------- Phase B: row replay (ascending n = numpy order) -----
    float bv = 0.0f;   // all-zero row: bv=0, bi=0 == numpy argmax
    int bi = 0;
    unsigned rms[4] = {rm0, rm1, rm2, rm3};
    #pragma unroll
    for (int h = 0; h < 4; h++) {
        unsigned m = rms[h];
        const int nb = h * 32;
        while (m) {
            int n = __builtin_ctz(m) + nb;
            m &= m - 1;
            float inter, uni;
            geom(axy, sg[n], area_a, sac[n].x, inter, uni);
            float qa = inter * __builtin_amdgcn_rcpf(uni);
            if (qa > 0.0f && qa >= rt) {             // final-threshold re-test
                float iou = inter / uni;             // exact IEEE == numpy
                if (iou > bv) { bv = iou; bi = n; }  // strict >: first max
            }
        }
    }

    if (valid) {
        // pos decision folded into the slot: exact bv vs 0.5 (override makes
        // pos true anyway; applied later via OVR table / OVR_FLAG).
        out_slot[(size_t)b * AA + a] = bi | (bv > 0.5f ? POS_BIT : 0);
    }
}

// ---------------------------------------------------------------------------
// FUSED encode: scatter folded in via LDS override table. Requires colmax
// outside out (ws). ovr[rel] = max n whose column winner is anchor abase+rel
// (atomicMax == np fancy-assignment last-n-wins). low==0 prior sentinel
// rejected by the low>=1 guard.
// ---------------------------------------------------------------------------
__global__ __launch_bounds__(256) void encode_fused_kernel(
        const int* __restrict__ gt_labels,
        const float4* __restrict__ gt_boxes,        // xyxy
        const float4* __restrict__ anchors_cxcywh,
        const unsigned long long* __restrict__ colmax,
        float* __restrict__ out)
{
    const int b = blockIdx.y;
    const int tid = threadIdx.x;
    const int abase = blockIdx.x * 256;

    __shared__ float4 sg[NN];
    __shared__ int    slab[NN];
    __shared__ int    ovr[256];

    ovr[tid] = -1;
    if (tid < NN) {
        sg[tid]   = gt_boxes[b * NN + tid];
        slab[tid] = gt_labels[b * NN + tid];
    }
    __syncthreads();
    if (tid < NN) {
        unsigned long long v = colmax[b * NN + tid];
        unsigned low = (unsigned)(v & 0xFFFFFFFFull);
        if (low >= 1u && low <= (unsigned)AA) {
            int rel = (AA - (int)low) - abase;       // column-winner anchor
            if (rel >= 0 && rel < 256) atomicMax(&ovr[rel], tid);
        }
    }
    __syncthreads();

    const int a = abase + tid;
    if (a >= AA) return;

    const size_t BA = (size_t)BB * AA;
    const size_t base = (size_t)b * AA + a;

    int s = ((const int*)(out + 5 * BA))[base];
    int o = ovr[tid];

    int idx; bool pos;
    if (o >= 0) { idx = o;          pos = true; }
    else        { idx = s & 0x7FFF; pos = (s & POS_BIT) != 0; }

    const float4 g = sg[idx];
    const float gcx = (g.x + g.z) * 0.5f;
    const float gcy = (g.y + g.w) * 0.5f;
    const float gw  = g.z - g.x;
    const float gh  = g.w - g.y;

    const float4 anc = anchors_cxcywh[a];
    const float ecx = (gcx - anc.x) / anc.z;
    const float ecy = (gcy - anc.y) / anc.w;
    const float ew  = logf((gw + EPS_F) / (anc.z + EPS_F));
    const float eh  = logf((gh + EPS_F) / (anc.w + EPS_F));

    out[base] = pos ? (float)slab[idx] : 0.0f;                   // labels
    ((float4*)(out + BA))[base] = make_float4(ecx, ecy, ew, eh); // boxes
    out[5 * BA + base] = pos ? 1.0f : 0.0f;                      // mask
}

// ---------------------------------------------------------------------------
// Fallback scatter + encode (HW-proven): used when ws_size < 51,200 B and
// colmax must alias out's boxes region.
// ---------------------------------------------------------------------------
__global__ void scatter_kernel(const unsigned long long* __restrict__ colmax,
                               int* __restrict__ out_slot) {
    const int b = blockIdx.x;
    const int n = threadIdx.x;
    if (n < NN) {
        unsigned long long v = colmax[b * NN + n];
        unsigned low = (unsigned)(v & 0xFFFFFFFFull);
        if (low >= 1u && low <= (unsigned)AA) {
            int idx = AA - (int)low;
            atomicMax(&out_slot[(size_t)b * AA + idx], OVR_FLAG + n);
        }
    }
}

__global__ __launch_bounds__(256) void encode_kernel(
        const int* __restrict__ gt_labels,
        const float4* __restrict__ gt_boxes,        // xyxy
        const float4* __restrict__ anchors_cxcywh,
        float* __restrict__ out)
{
    const int b = blockIdx.y;
    const int tid = threadIdx.x;
    const int a = blockIdx.x * 256 + tid;

    __shared__ float4 sg[NN];
    __shared__ int    slab[NN];
    if (tid < NN) {
        sg[tid]   = gt_boxes[b * NN + tid];
        slab[tid] = gt_labels[b * NN + tid];
    }
    __syncthreads();
    if (a >= AA) return;

    const size_t BA = (size_t)BB * AA;
    const size_t base = (size_t)b * AA + a;

    int s = ((const int*)(out + 5 * BA))[base];

    int idx; bool pos;
    if (s >= OVR_FLAG) { idx = s - OVR_FLAG;  pos = true; }
    else               { idx = s & 0x7FFF;    pos = (s & POS_BIT) != 0; }

    const float4 g = sg[idx];
    const float gcx = (g.x + g.z) * 0.5f;
    const float gcy = (g.y + g.w) * 0.5f;
    const float gw  = g.z - g.x;
    const float gh  = g.w - g.y;

    const float4 anc = anchors_cxcywh[a];
    const float ecx = (gcx - anc.x) / anc.z;
    const float ecy = (gcy - anc.y) / anc.w;
    const float ew  = logf((gw + EPS_F) / (anc.z + EPS_F));
    const float eh  = logf((gh + EPS_F) / (anc.w + EPS_F));

    out[base] = pos ? (float)slab[idx] : 0.0f;                   // labels
    ((float4*)(out + BA))[base] = make_float4(ecx, ecy, ew, eh); // boxes
    out[5 * BA + base] = pos ? 1.0f : 0.0f;                      // mask
}

extern "C" void kernel_launch(void* const* d_in, const int* in_sizes, int n_in,
                              void* d_out, int out_size, void* d_ws, size_t ws_size,
                              hipStream_t stream) {
    const int*    gt_labels    = (const int*)d_in[0];
    const float4* gt_boxes     = (const float4*)d_in[1];
    const float4* anchors_cxcy = (const float4*)d_in[2];
    const float4* anchors_xyxy = (const float4*)d_in[3];
    float* out = (float*)d_out;

    const size_t BA = (size_t)BB * AA;
    int* slot = (int*)(out + 5 * BA);

    // Fused path needs colmax (B*N u64 = 51,200 B) to live outside out,
    // because encode overwrites the boxes region that hosts colmax in the
    // fallback. d_ws proven >= 25,600 B; check for the larger need at runtime.
    const bool fused = (ws_size >= (size_t)(BB * NN * 8));
    unsigned long long* colmax = fused
        ? (unsigned long long*)d_ws                  // 8B-aligned ws
        : (unsigned long long*)(out + BA);           // boxes region (proven)

    prior_kernel<<<BB, 128, 0, stream>>>(gt_boxes, anchors_xyxy, colmax);

    dim3 grid(NTILE, BB);    // (35, 64) — 1 anchor/thread
    iou_pass_kernel<<<grid, 256, 0, stream>>>(gt_boxes, anchors_xyxy,
                                              colmax, slot);
    if (fused) {
        encode_fused_kernel<<<grid, 256, 0, stream>>>(gt_labels, gt_boxes,
                                                      anchors_cxcy, colmax,
                                                      out);
    } else {
        scatter_kernel<<<BB, 128, 0, stream>>>(colmax, slot);
        encode_kernel<<<grid, 256, 0, stream>>>(gt_labels, gt_boxes,
                                                anchors_cxcy, out);
    }
}